// Round 4
// baseline (834.227 us; speedup 1.0000x reference)
//
#include <hip/hip_runtime.h>
#include <math.h>

#define EMB 1024
#define FF  4096
#define NE  8
#define TTOK 8192

typedef __attribute__((ext_vector_type(4))) float  f32x4;
typedef __attribute__((ext_vector_type(8))) __bf16 bf16x8;

#define MAXROWS  18432   // 16384 assignments + 8*256 padding
// tiles: <= 16384/256 + 8 = 72

// ---- ws layout (bytes) ----
#define WS_COUNTS  0        // int[8*32]
#define WS_CURSORS 1024     // int[8]
#define WS_SSUM    1056     // float[8*32]
#define WS_NTILES  2080     // int
#define WS_BASE    2084     // int[8]
#define WS_TILE_E  2176     // int[160]
#define WS_TILE_RB 2816     // int[160..]
#define WS_TKIDX   4096     // int[2*TTOK]            -> 69632
#define WS_TKW     69632    // float[2*TTOK]          -> 135168
#define WS_SLOT    135168   // int[2*TTOK]            -> 200704
#define WS_TOKID   200704   // int[MAXROWS]           -> 274432
#define WS_ROWW    274432   // float[MAXROWS]         -> 348160
#define WS_ZP      348160   // __bf16[1024] zeros     -> 350208
#define WS_BIG2    350208   // [W1T | xb | W2T | h | (y)]

#define SZ_W1T ((size_t)NE * EMB * FF * 2)   // 64 MB
#define SZ_W2T ((size_t)NE * EMB * FF * 2)   // 64 MB
#define SZ_XB  ((size_t)TTOK * EMB * 2)      // 16 MB

__device__ inline f32x4 fzero() { f32x4 v = {0.f, 0.f, 0.f, 0.f}; return v; }

__device__ __forceinline__ void gl16(const void* g, void* l) {
    __builtin_amdgcn_global_load_lds(
        (const __attribute__((address_space(1))) void*)g,
        (__attribute__((address_space(3))) void*)l, 16, 0, 0);
}

// ---------------- gating ----------------
__global__ __launch_bounds__(256) void gate_kernel(
    const float* __restrict__ x, const float* __restrict__ gW, const float* __restrict__ gb,
    int* counts, float* ssum, int* tk_idx, float* tk_w)
{
    int wave = threadIdx.x >> 6;
    int lane = threadIdx.x & 63;
    int t = blockIdx.x * 4 + wave;

    float acc[NE];
#pragma unroll
    for (int e = 0; e < NE; e++) acc[e] = 0.f;

    const float* xr = x + (size_t)t * EMB;
#pragma unroll
    for (int i = 0; i < 4; i++) {
        int d0 = i * 256 + lane * 4;
        f32x4 xv = *(const f32x4*)(xr + d0);
#pragma unroll
        for (int j = 0; j < 4; j++) {
            const float* wrow = gW + (size_t)(d0 + j) * NE;
            float xs = xv[j];
#pragma unroll
            for (int e = 0; e < NE; e++) acc[e] += xs * wrow[e];
        }
    }
#pragma unroll
    for (int e = 0; e < NE; e++) {
#pragma unroll
        for (int off = 32; off; off >>= 1) acc[e] += __shfl_xor(acc[e], off, 64);
    }
    if (lane == 0) {
        float sc[NE];
        float m = -1e30f;
        for (int e = 0; e < NE; e++) { sc[e] = acc[e] + gb[e]; m = fmaxf(m, sc[e]); }
        float sum = 0.f;
        for (int e = 0; e < NE; e++) { sc[e] = expf(sc[e] - m); sum += sc[e]; }
        float inv = 1.f / sum;
        for (int e = 0; e < NE; e++) sc[e] *= inv;
        int i0 = 0; float s0 = sc[0];
        for (int e = 1; e < NE; e++) if (sc[e] > s0) { s0 = sc[e]; i0 = e; }
        int i1 = -1; float s1 = -1e30f;
        for (int e = 0; e < NE; e++) if (e != i0 && sc[e] > s1) { s1 = sc[e]; i1 = e; }
        float rn = 1.f / (s0 + s1);
        tk_idx[2 * t]     = i0;  tk_idx[2 * t + 1] = i1;
        tk_w[2 * t]       = s0 * rn;  tk_w[2 * t + 1] = s1 * rn;
        int slot = blockIdx.x & 31;
        atomicAdd(&counts[i0 * 32 + slot], 1);
        atomicAdd(&counts[i1 * 32 + slot], 1);
        for (int e = 0; e < NE; e++) atomicAdd(&ssum[e * 32 + slot], sc[e]);
    }
}

// ---------------- routing tables + aux (pad to 256-row tiles) ----------------
__global__ void route_build_kernel(const int* counts, const float* ssum,
                                   int* ntiles, int* base, int* tile_e, int* tile_rb,
                                   float* out_aux)
{
    if (threadIdx.x != 0 || blockIdx.x != 0) return;
    int total = 0, tiles = 0;
    float aux = 0.f;
    for (int e = 0; e < NE; e++) {
        int c = 0; float ss = 0.f;
        for (int j = 0; j < 32; j++) { c += counts[e * 32 + j]; ss += ssum[e * 32 + j]; }
        base[e] = total;
        int nt = (c + 255) >> 8;
        for (int i = 0; i < nt; i++) { tile_e[tiles] = e; tile_rb[tiles] = total + (i << 8); tiles++; }
        total += nt << 8;
        aux += ((float)c / (float)(TTOK * 2)) * (ss / (float)TTOK);
    }
    *ntiles = tiles;
    *out_aux = aux * (float)NE;
}

__global__ __launch_bounds__(256) void scatter_kernel(
    const int* __restrict__ tk_idx, const float* __restrict__ tk_w,
    const int* __restrict__ base, int* cursors, int* token_id, float* roww,
    int* slot_of)
{
    int t = blockIdx.x * 256 + threadIdx.x;
#pragma unroll
    for (int k = 0; k < 2; k++) {
        int e = tk_idx[2 * t + k];
        int pos = atomicAdd(&cursors[e], 1);
        int slot = base[e] + pos;
        token_id[slot] = t;
        roww[slot] = tk_w[2 * t + k];
        slot_of[2 * t + k] = slot;
    }
}

// ---------------- combine: out[t] = w0*(y[s0]+b2[e0]) + w1*(y[s1]+b2[e1]) ----------------
__global__ __launch_bounds__(256) void combine_kernel(
    const float* __restrict__ y, const int* __restrict__ slot_of,
    const int* __restrict__ tk_idx, const float* __restrict__ tk_w,
    const float* __restrict__ b2, float* __restrict__ out)
{
    int t = blockIdx.x;
    int dq = threadIdx.x * 4;
    int s0 = slot_of[2 * t], s1 = slot_of[2 * t + 1];
    int e0 = tk_idx[2 * t], e1 = tk_idx[2 * t + 1];
    float w0 = tk_w[2 * t], w1 = tk_w[2 * t + 1];
    f32x4 ya = *(const f32x4*)(y + (size_t)s0 * EMB + dq);
    f32x4 yb = *(const f32x4*)(y + (size_t)s1 * EMB + dq);
    f32x4 ba = *(const f32x4*)(b2 + (size_t)e0 * EMB + dq);
    f32x4 bb = *(const f32x4*)(b2 + (size_t)e1 * EMB + dq);
    f32x4 r;
#pragma unroll
    for (int q = 0; q < 4; q++) r[q] = w0 * (ya[q] + ba[q]) + w1 * (yb[q] + bb[q]);
    *(f32x4*)(out + (size_t)t * EMB + dq) = r;
}

// ---------------- converts ----------------
__global__ __launch_bounds__(256) void cvt_x_kernel(const float* __restrict__ x, __bf16* __restrict__ xb)
{
    size_t i = ((size_t)blockIdx.x * 256 + threadIdx.x) * 8;
    f32x4 a = *(const f32x4*)(x + i);
    f32x4 b = *(const f32x4*)(x + i + 4);
    bf16x8 o;
#pragma unroll
    for (int q = 0; q < 4; q++) { o[q] = (__bf16)a[q]; o[q + 4] = (__bf16)b[q]; }
    *(bf16x8*)(xb + i) = o;
}

// in [R][C] fp32 per expert -> out [C][R] bf16 per expert. grid (R/64, C/64, NE)
__global__ __launch_bounds__(256) void transpose_cvt_kernel(
    const float* __restrict__ in, __bf16* __restrict__ outb, int R, int C)
{
    int e = blockIdx.z;
    const float* src = in + (size_t)e * R * C;
    __bf16* dst = outb + (size_t)e * R * C;
    __shared__ __bf16 Ls[64 * 72];
    int t = threadIdx.x;
    int r0 = blockIdx.x * 64, c0 = blockIdx.y * 64;
    int ri = t >> 4, cj = (t & 15) * 4;
#pragma unroll
    for (int p = 0; p < 4; p++) {
        int r = ri + p * 16;
        f32x4 v = *(const f32x4*)(src + (size_t)(r0 + r) * C + c0 + cj);
#pragma unroll
        for (int q = 0; q < 4; q++) Ls[(cj + q) * 72 + r] = (__bf16)v[q];
    }
    __syncthreads();
    int c = t >> 2, rq = (t & 3) * 16;
    bf16x8 a = *(bf16x8*)&Ls[c * 72 + rq];
    bf16x8 b = *(bf16x8*)&Ls[c * 72 + rq + 8];
    *(bf16x8*)(dst + (size_t)(c0 + c) * R + r0 + rq) = a;
    *(bf16x8*)(dst + (size_t)(c0 + c) * R + r0 + rq + 8) = b;
}

// ============================================================================
// Grouped GEMMs: BM=256, BN=128, BK=32, 256 threads (4 waves as 2Mx2N),
// wave tile 128x64 -> acc[8][4]. gl16 staging with source-side XOR chunk
// swizzle (involution, read-side applies same XOR). Double-buffer, one
// __syncthreads per K-step (compiler drains vmcnt before barrier).
// Grid: flat, XCD-chunked (c8 = flat&7), nb-fastest for A-tile L2 reuse.
// ============================================================================

// h = gelu(xb[tok] @ W1T[e]^T + b1[e]); K = EMB. chunk splits FF (N dim).
__global__ __launch_bounds__(256, 2) void gemm1_f256(
    const __bf16* __restrict__ xb, const __bf16* __restrict__ W1T,
    const float* __restrict__ b1, const __bf16* __restrict__ zp,
    const int* __restrict__ token_id, const int* __restrict__ tile_e,
    const int* __restrict__ tile_rb, const int* __restrict__ ntiles,
    __bf16* __restrict__ h, int ffc, int chunk, int nbt)
{
    int flat = blockIdx.x;
    int c8 = flat & 7; int r = flat >> 3;
    int mti = r / nbt, nb = r - mti * nbt;
    int mt = c8 * 9 + mti;
    if (mt >= *ntiles) return;
    int e = tile_e[mt], rb = tile_rb[mt];
    int n0 = nb * 128;
    int nglob = chunk * ffc + n0;

    __shared__ __bf16 As[2][8192];   // [256 rows][32 k]
    __shared__ __bf16 Bs[2][4096];   // [128 rows][32 k]

    int tid = threadIdx.x, lane = tid & 63, wave = tid >> 6;
    int wr = wave >> 1, wc = wave & 1;

    int lrow = lane >> 2;
    int srcoff = (((lane & 3) ^ ((lane >> 3) & 3)) << 3);

    const __bf16* asrc[4];
#pragma unroll
    for (int p = 0; p < 4; p++) {
        int row = p * 64 + wave * 16 + lrow;
        int tok = token_id[rb + row];
        asrc[p] = (tok >= 0 ? xb + (size_t)tok * EMB : zp) + srcoff;
    }
    const __bf16* bsrc[2];
#pragma unroll
    for (int p = 0; p < 2; p++)
        bsrc[p] = W1T + (size_t)e * FF * EMB
                + (size_t)(nglob + p * 64 + wave * 16 + lrow) * EMB + srcoff;

    f32x4 acc[8][4];
#pragma unroll
    for (int i = 0; i < 8; i++)
#pragma unroll
        for (int j = 0; j < 4; j++) acc[i][j] = fzero();

    int cl = lane & 15, cq = lane >> 4;
    int xoff = ((cq ^ ((cl >> 1) & 3)) << 3);

    auto stage = [&](int buf, int k0) {
#pragma unroll
        for (int p = 0; p < 4; p++) gl16(asrc[p] + k0, &As[buf][(p * 64 + wave * 16) * 32]);
#pragma unroll
        for (int p = 0; p < 2; p++) gl16(bsrc[p] + k0, &Bs[buf][(p * 64 + wave * 16) * 32]);
    };

    stage(0, 0);
    __syncthreads();

#pragma unroll 2
    for (int t = 0; t < 32; t++) {
        if (t < 31) stage((t + 1) & 1, (t + 1) * 32);
        int cb = t & 1;
        bf16x8 af[8], bv[4];
#pragma unroll
        for (int mi = 0; mi < 8; mi++)
            af[mi] = *(const bf16x8*)&As[cb][(wr * 128 + mi * 16 + cl) * 32 + xoff];
#pragma unroll
        for (int ni = 0; ni < 4; ni++)
            bv[ni] = *(const bf16x8*)&Bs[cb][(wc * 64 + ni * 16 + cl) * 32 + xoff];
#pragma unroll
        for (int mi = 0; mi < 8; mi++)
#pragma unroll
            for (int ni = 0; ni < 4; ni++)
                acc[mi][ni] = __builtin_amdgcn_mfma_f32_16x16x32_bf16(af[mi], bv[ni], acc[mi][ni], 0, 0, 0);
        __syncthreads();
    }

    const float* b1g = b1 + (size_t)e * FF + nglob;
    int r0q = (lane >> 4) * 4;
#pragma unroll
    for (int mi = 0; mi < 8; mi++) {
#pragma unroll
        for (int ni = 0; ni < 4; ni++) {
            int col = wc * 64 + ni * 16 + cl;
            float bias = b1g[col];
#pragma unroll
            for (int j = 0; j < 4; j++) {
                int row = wr * 128 + mi * 16 + r0q + j;
                float v = acc[mi][ni][j] + bias;
                v = 0.5f * v * (1.0f + erff(v * 0.70710678118654752f));
                h[(size_t)(rb + row) * ffc + n0 + col] = (__bf16)v;
            }
        }
    }
}

// y[slot] (+)= h[slot] @ W2T[e]^T ; K = ffc (chunk splits K). N = EMB.
__global__ __launch_bounds__(256, 2) void gemm2_f256(
    const __bf16* __restrict__ h, const __bf16* __restrict__ W2T,
    const int* __restrict__ tile_e, const int* __restrict__ tile_rb,
    const int* __restrict__ ntiles, float* __restrict__ y, int ffc, int chunk)
{
    int flat = blockIdx.x;
    int c8 = flat & 7; int r = flat >> 3;
    int mti = r >> 3, nb = r & 7;
    int mt = c8 * 9 + mti;
    if (mt >= *ntiles) return;
    int e = tile_e[mt], rb = tile_rb[mt];
    int n0 = nb * 128;

    __shared__ __bf16 As[2][8192];
    __shared__ __bf16 Bs[2][4096];

    int tid = threadIdx.x, lane = tid & 63, wave = tid >> 6;
    int wr = wave >> 1, wc = wave & 1;

    int lrow = lane >> 2;
    int srcoff = (((lane & 3) ^ ((lane >> 3) & 3)) << 3);

    const __bf16* asrc[4];
#pragma unroll
    for (int p = 0; p < 4; p++)
        asrc[p] = h + (size_t)(rb + p * 64 + wave * 16 + lrow) * ffc + srcoff;
    const __bf16* bsrc[2];
#pragma unroll
    for (int p = 0; p < 2; p++)
        bsrc[p] = W2T + (size_t)e * EMB * FF
                + (size_t)(n0 + p * 64 + wave * 16 + lrow) * FF + (size_t)chunk * ffc + srcoff;

    f32x4 acc[8][4];
#pragma unroll
    for (int i = 0; i < 8; i++)
#pragma unroll
        for (int j = 0; j < 4; j++) acc[i][j] = fzero();

    int cl = lane & 15, cq = lane >> 4;
    int xoff = ((cq ^ ((cl >> 1) & 3)) << 3);

    auto stage = [&](int buf, int k0) {
#pragma unroll
        for (int p = 0; p < 4; p++) gl16(asrc[p] + k0, &As[buf][(p * 64 + wave * 16) * 32]);
#pragma unroll
        for (int p = 0; p < 2; p++) gl16(bsrc[p] + k0, &Bs[buf][(p * 64 + wave * 16) * 32]);
    };

    stage(0, 0);
    __syncthreads();

    int ks = ffc >> 5;
#pragma unroll 2
    for (int t = 0; t < ks; t++) {
        if (t < ks - 1) stage((t + 1) & 1, (t + 1) * 32);
        int cb = t & 1;
        bf16x8 af[8], bv[4];
#pragma unroll
        for (int mi = 0; mi < 8; mi++)
            af[mi] = *(const bf16x8*)&As[cb][(wr * 128 + mi * 16 + cl) * 32 + xoff];
#pragma unroll
        for (int ni = 0; ni < 4; ni++)
            bv[ni] = *(const bf16x8*)&Bs[cb][(wc * 64 + ni * 16 + cl) * 32 + xoff];
#pragma unroll
        for (int mi = 0; mi < 8; mi++)
#pragma unroll
            for (int ni = 0; ni < 4; ni++)
                acc[mi][ni] = __builtin_amdgcn_mfma_f32_16x16x32_bf16(af[mi], bv[ni], acc[mi][ni], 0, 0, 0);
        __syncthreads();
    }

    int r0q = (lane >> 4) * 4;
#pragma unroll
    for (int mi = 0; mi < 8; mi++) {
#pragma unroll
        for (int ni = 0; ni < 4; ni++) {
            int col = wc * 64 + ni * 16 + cl;
#pragma unroll
            for (int j = 0; j < 4; j++) {
                int row = wr * 128 + mi * 16 + r0q + j;
                float* yp = y + (size_t)(rb + row) * EMB + n0 + col;
                float v = acc[mi][ni][j];
                if (chunk) v += *yp;
                *yp = v;
            }
        }
    }
}

extern "C" void kernel_launch(void* const* d_in, const int* in_sizes, int n_in,
                              void* d_out, int out_size, void* d_ws, size_t ws_size,
                              hipStream_t stream)
{
    const float* x   = (const float*)d_in[0];
    const float* gW  = (const float*)d_in[1];
    const float* gb  = (const float*)d_in[2];
    const float* W1  = (const float*)d_in[3];
    const float* b1  = (const float*)d_in[4];
    const float* W2  = (const float*)d_in[5];
    const float* b2  = (const float*)d_in[6];
    float* out = (float*)d_out;

    char* ws = (char*)d_ws;
    int*   counts  = (int*)(ws + WS_COUNTS);
    int*   cursors = (int*)(ws + WS_CURSORS);
    float* ssum    = (float*)(ws + WS_SSUM);
    int*   ntiles  = (int*)(ws + WS_NTILES);
    int*   base    = (int*)(ws + WS_BASE);
    int*   tile_e  = (int*)(ws + WS_TILE_E);
    int*   tile_rb = (int*)(ws + WS_TILE_RB);
    int*   tk_idx  = (int*)(ws + WS_TKIDX);
    float* tk_w    = (float*)(ws + WS_TKW);
    int*   slot_of = (int*)(ws + WS_SLOT);
    int*   token_id= (int*)(ws + WS_TOKID);
    float* roww    = (float*)(ws + WS_ROWW);
    __bf16* zp     = (__bf16*)(ws + WS_ZP);

    __bf16* W1T  = (__bf16*)(ws + WS_BIG2);
    __bf16* xb   = (__bf16*)(ws + WS_BIG2 + SZ_W1T);
    __bf16* W2T  = (__bf16*)(ws + WS_BIG2 + SZ_W1T + SZ_XB);
    __bf16* hbuf = (__bf16*)(ws + WS_BIG2 + SZ_W1T + SZ_XB + SZ_W2T);
    size_t fixedend = WS_BIG2 + SZ_W1T + SZ_XB + SZ_W2T;

    int ffc; float* ybuf;
    if (ws_size >= fixedend + (size_t)MAXROWS * 4096 * 2) {
        ffc = 4096;
        ybuf = (float*)(ws + WS_BIG2);   // aliases W1T+xb (dead after gemm1; 75.5MB <= 80MB)
    } else if (ws_size >= fixedend + (size_t)MAXROWS * 1024 * 2 + (size_t)MAXROWS * EMB * 4) {
        ffc = 1024;
        ybuf = (float*)(ws + fixedend + (size_t)MAXROWS * 1024 * 2);
    } else {
        ffc = 512;
        ybuf = (float*)(ws + fixedend + (size_t)MAXROWS * 512 * 2);
    }

    hipMemsetAsync(ws + WS_COUNTS, 0, 2080, stream);
    hipMemsetAsync(ws + WS_TOKID, 0xFF, (size_t)MAXROWS * 4, stream);
    hipMemsetAsync(ws + WS_ZP, 0, 2048, stream);

    cvt_x_kernel<<<TTOK * EMB / 2048, 256, 0, stream>>>(x, xb);
    transpose_cvt_kernel<<<dim3(EMB / 64, FF / 64, NE), 256, 0, stream>>>(W1, W1T, EMB, FF);
    transpose_cvt_kernel<<<dim3(FF / 64, EMB / 64, NE), 256, 0, stream>>>(W2, W2T, FF, EMB);

    gate_kernel<<<TTOK / 4, 256, 0, stream>>>(x, gW, gb, counts, ssum, tk_idx, tk_w);
    route_build_kernel<<<1, 64, 0, stream>>>(counts, ssum, ntiles, base, tile_e, tile_rb,
                                             out + (size_t)TTOK * EMB);
    scatter_kernel<<<TTOK / 256, 256, 0, stream>>>(tk_idx, tk_w, base, cursors, token_id, roww, slot_of);

    int nchunks = FF / ffc;
    for (int c = 0; c < nchunks; c++) {
        gemm1_f256<<<8 * 9 * (ffc / 128), 256, 0, stream>>>(
            xb, W1T, b1, zp, token_id, tile_e, tile_rb, ntiles, hbuf, ffc, c, ffc / 128);
        gemm2_f256<<<8 * 9 * 8, 256, 0, stream>>>(
            hbuf, W2T, tile_e, tile_rb, ntiles, ybuf, ffc, c);
    }
    combine_kernel<<<TTOK, 256, 0, stream>>>(ybuf, slot_of, tk_idx, tk_w, b2, out);
}

// Round 5
// 708.438 us; speedup vs baseline: 1.1776x; 1.1776x over previous
//
#include <hip/hip_runtime.h>
#include <math.h>

#define EMB 1024
#define FF  4096
#define NE  8
#define TTOK 8192

typedef __attribute__((ext_vector_type(4))) float  f32x4;
typedef __attribute__((ext_vector_type(8))) __bf16 bf16x8;

#define MAXROWS  18432   // 16384 assignments + 8*256 padding
// m-tiles (256-row): <= 16384/256 + 8 = 72

// ---- ws layout (bytes) ----
#define WS_COUNTS  0        // int[8*32]
#define WS_CURSORS 1024     // int[8]
#define WS_SSUM    1056     // float[8*32]
#define WS_NTILES  2080     // int
#define WS_BASE    2084     // int[8]
#define WS_TILE_E  2176     // int[160]
#define WS_TILE_RB 2816     // int[160..]
#define WS_TKIDX   4096     // int[2*TTOK]
#define WS_TKW     69632    // float[2*TTOK]
#define WS_SLOT    135168   // int[2*TTOK]
#define WS_TOKID   200704   // int[MAXROWS]
#define WS_ROWW    274432   // float[MAXROWS]
#define WS_BIG2    350208   // [W1T | xb | W2T | h | (y1)]

#define SZ_W1T ((size_t)NE * EMB * FF * 2)   // 64 MB
#define SZ_W2T ((size_t)NE * EMB * FF * 2)   // 64 MB
#define SZ_XB  ((size_t)TTOK * EMB * 2)      // 16 MB
#define SZ_H   ((size_t)MAXROWS * FF * 2)    // 144 MB
#define SZ_Y   ((size_t)MAXROWS * EMB * 4)   // 72 MB

__device__ inline f32x4 fzero() { f32x4 v = {0.f, 0.f, 0.f, 0.f}; return v; }

__device__ __forceinline__ void gl16(const void* g, void* l) {
    __builtin_amdgcn_global_load_lds(
        (const __attribute__((address_space(1))) void*)g,
        (__attribute__((address_space(3))) void*)l, 16, 0, 0);
}

// fast erf-gelu (A&S 7.1.25, |erf err| <= 5e-4; bf16 h quantization dominates)
__device__ __forceinline__ float gelu_f(float v) {
    float u = fabsf(v) * 0.70710678118654752f;
    float p = 1.0f + u * (0.278393f + u * (0.230389f + u * (0.000972f + u * 0.078108f)));
    p = p * p; p = p * p;
    float er = 1.0f - 1.0f / p;
    float s = (v >= 0.0f) ? er : -er;
    return 0.5f * v * (1.0f + s);
}

// ---------------- gating ----------------
__global__ __launch_bounds__(256) void gate_kernel(
    const float* __restrict__ x, const float* __restrict__ gW, const float* __restrict__ gb,
    int* counts, float* ssum, int* tk_idx, float* tk_w)
{
    int wave = threadIdx.x >> 6;
    int lane = threadIdx.x & 63;
    int t = blockIdx.x * 4 + wave;

    float acc[NE];
#pragma unroll
    for (int e = 0; e < NE; e++) acc[e] = 0.f;

    const float* xr = x + (size_t)t * EMB;
#pragma unroll
    for (int i = 0; i < 4; i++) {
        int d0 = i * 256 + lane * 4;
        f32x4 xv = *(const f32x4*)(xr + d0);
#pragma unroll
        for (int j = 0; j < 4; j++) {
            const float* wrow = gW + (size_t)(d0 + j) * NE;
            float xs = xv[j];
#pragma unroll
            for (int e = 0; e < NE; e++) acc[e] += xs * wrow[e];
        }
    }
#pragma unroll
    for (int e = 0; e < NE; e++) {
#pragma unroll
        for (int off = 32; off; off >>= 1) acc[e] += __shfl_xor(acc[e], off, 64);
    }
    if (lane == 0) {
        float sc[NE];
        float m = -1e30f;
        for (int e = 0; e < NE; e++) { sc[e] = acc[e] + gb[e]; m = fmaxf(m, sc[e]); }
        float sum = 0.f;
        for (int e = 0; e < NE; e++) { sc[e] = expf(sc[e] - m); sum += sc[e]; }
        float inv = 1.f / sum;
        for (int e = 0; e < NE; e++) sc[e] *= inv;
        int i0 = 0; float s0 = sc[0];
        for (int e = 1; e < NE; e++) if (sc[e] > s0) { s0 = sc[e]; i0 = e; }
        int i1 = -1; float s1 = -1e30f;
        for (int e = 0; e < NE; e++) if (e != i0 && sc[e] > s1) { s1 = sc[e]; i1 = e; }
        float rn = 1.f / (s0 + s1);
        tk_idx[2 * t]     = i0;  tk_idx[2 * t + 1] = i1;
        tk_w[2 * t]       = s0 * rn;  tk_w[2 * t + 1] = s1 * rn;
        int slot = blockIdx.x & 31;
        atomicAdd(&counts[i0 * 32 + slot], 1);
        atomicAdd(&counts[i1 * 32 + slot], 1);
        for (int e = 0; e < NE; e++) atomicAdd(&ssum[e * 32 + slot], sc[e]);
    }
}

// ---------------- routing tables + aux (pad to 256-row tiles) ----------------
__global__ void route_build_kernel(const int* counts, const float* ssum,
                                   int* ntiles, int* base, int* tile_e, int* tile_rb,
                                   float* out_aux)
{
    if (threadIdx.x != 0 || blockIdx.x != 0) return;
    int total = 0, tiles = 0;
    float aux = 0.f;
    for (int e = 0; e < NE; e++) {
        int c = 0; float ss = 0.f;
        for (int j = 0; j < 32; j++) { c += counts[e * 32 + j]; ss += ssum[e * 32 + j]; }
        base[e] = total;
        int nt = (c + 255) >> 8;
        for (int i = 0; i < nt; i++) { tile_e[tiles] = e; tile_rb[tiles] = total + (i << 8); tiles++; }
        total += nt << 8;
        aux += ((float)c / (float)(TTOK * 2)) * (ss / (float)TTOK);
    }
    *ntiles = tiles;
    *out_aux = aux * (float)NE;
}

__global__ __launch_bounds__(256) void scatter_kernel(
    const int* __restrict__ tk_idx, const float* __restrict__ tk_w,
    const int* __restrict__ base, int* cursors, int* token_id, float* roww,
    int* slot_of)
{
    int t = blockIdx.x * 256 + threadIdx.x;
#pragma unroll
    for (int k = 0; k < 2; k++) {
        int e = tk_idx[2 * t + k];
        int pos = atomicAdd(&cursors[e], 1);
        int slot = base[e] + pos;
        token_id[slot] = t;
        roww[slot] = tk_w[2 * t + k];
        slot_of[2 * t + k] = slot;
    }
}

// ---------------- combine: out[t] = sum_k w_k*(y[s_k]+b2[e_k]) ----------------
__global__ __launch_bounds__(256) void combine_kernel(
    const float* __restrict__ y0, const float* __restrict__ y1, int nsplit,
    const int* __restrict__ slot_of,
    const int* __restrict__ tk_idx, const float* __restrict__ tk_w,
    const float* __restrict__ b2, float* __restrict__ out)
{
    int t = blockIdx.x;
    int dq = threadIdx.x * 4;
    int s0 = slot_of[2 * t], s1 = slot_of[2 * t + 1];
    int e0 = tk_idx[2 * t], e1 = tk_idx[2 * t + 1];
    float w0 = tk_w[2 * t], w1 = tk_w[2 * t + 1];
    f32x4 ya = *(const f32x4*)(y0 + (size_t)s0 * EMB + dq);
    f32x4 yb = *(const f32x4*)(y0 + (size_t)s1 * EMB + dq);
    if (nsplit == 2) {
        f32x4 za = *(const f32x4*)(y1 + (size_t)s0 * EMB + dq);
        f32x4 zb = *(const f32x4*)(y1 + (size_t)s1 * EMB + dq);
#pragma unroll
        for (int q = 0; q < 4; q++) { ya[q] += za[q]; yb[q] += zb[q]; }
    }
    f32x4 ba = *(const f32x4*)(b2 + (size_t)e0 * EMB + dq);
    f32x4 bb = *(const f32x4*)(b2 + (size_t)e1 * EMB + dq);
    f32x4 r;
#pragma unroll
    for (int q = 0; q < 4; q++) r[q] = w0 * (ya[q] + ba[q]) + w1 * (yb[q] + bb[q]);
    *(f32x4*)(out + (size_t)t * EMB + dq) = r;
}

// ---------------- converts ----------------
__global__ __launch_bounds__(256) void cvt_x_kernel(const float* __restrict__ x, __bf16* __restrict__ xb)
{
    size_t i = ((size_t)blockIdx.x * 256 + threadIdx.x) * 8;
    f32x4 a = *(const f32x4*)(x + i);
    f32x4 b = *(const f32x4*)(x + i + 4);
    bf16x8 o;
#pragma unroll
    for (int q = 0; q < 4; q++) { o[q] = (__bf16)a[q]; o[q + 4] = (__bf16)b[q]; }
    *(bf16x8*)(xb + i) = o;
}

// in [R][C] fp32 per expert -> out [C][R] bf16 per expert. grid (R/64, C/64, NE)
__global__ __launch_bounds__(256) void transpose_cvt_kernel(
    const float* __restrict__ in, __bf16* __restrict__ outb, int R, int C)
{
    int e = blockIdx.z;
    const float* src = in + (size_t)e * R * C;
    __bf16* dst = outb + (size_t)e * R * C;
    __shared__ __bf16 Ls[64 * 72];
    int t = threadIdx.x;
    int r0 = blockIdx.x * 64, c0 = blockIdx.y * 64;
    int ri = t >> 4, cj = (t & 15) * 4;
#pragma unroll
    for (int p = 0; p < 4; p++) {
        int r = ri + p * 16;
        f32x4 v = *(const f32x4*)(src + (size_t)(r0 + r) * C + c0 + cj);
#pragma unroll
        for (int q = 0; q < 4; q++) Ls[(cj + q) * 72 + r] = (__bf16)v[q];
    }
    __syncthreads();
    int c = t >> 2, rq = (t & 3) * 16;
    bf16x8 a = *(bf16x8*)&Ls[c * 72 + rq];
    bf16x8 b = *(bf16x8*)&Ls[c * 72 + rq + 8];
    *(bf16x8*)(dst + (size_t)(c0 + c) * R + r0 + rq) = a;
    *(bf16x8*)(dst + (size_t)(c0 + c) * R + r0 + rq + 8) = b;
}

// ============================================================================
// 8-phase grouped GEMM: BM=256, BN=256, BK=32, 512 thr (8 waves 2Mx4N),
// wave tile 128x64 (acc[8][4]). Triple-buffered LDS (3 x 32KB), stages issue
// 2 K-tiles ahead via global_load_lds(16B) with source-side XOR chunk swizzle
// (involution; read side applies same XOR -> measured 0 bank conflicts).
// Per K-tile: 2 phases x {ds_read / 2 gl16 / barrier / lgkmcnt(0) /
// setprio(1) 16 MFMA setprio(0) / barrier}; counted s_waitcnt vmcnt(4) once
// per K-tile (vmcnt(0) only at tile NT-2). LDS elem layout per buf (16384):
//   A: [mhalf][128][32] at 0, B: [nhalf][128][32] at 8192; chunk slot =
//   c ^ ((row>>1)&3) on 8-elem chunks.
// ============================================================================

__device__ __forceinline__ void read_frags(const __bf16* lds, const int* off, bf16x8* v, int n) {
#pragma unroll 4
    for (int i = 0; i < n; i++) v[i] = *(const bf16x8*)(lds + off[i]);
}

#define GEMM_PHASE(AV, BV, ACCROW)                                                    \
    __builtin_amdgcn_s_barrier();                                                     \
    asm volatile("s_waitcnt lgkmcnt(0)" ::: "memory");                                \
    __builtin_amdgcn_sched_barrier(0);                                                \
    __builtin_amdgcn_s_setprio(1);                                                    \
    _Pragma("unroll")                                                                 \
    for (int mi = 0; mi < 4; mi++)                                                    \
        _Pragma("unroll")                                                             \
        for (int ni = 0; ni < 4; ni++)                                                \
            acc[ACCROW + mi][ni] = __builtin_amdgcn_mfma_f32_16x16x32_bf16(           \
                AV[mi], BV[ni], acc[ACCROW + mi][ni], 0, 0, 0);                       \
    __builtin_amdgcn_s_setprio(0);

// h = gelu(xb[tok] @ W1T[e]^T + b1[e]); K = EMB (32 K-tiles), N-tile = 256.
__global__ __launch_bounds__(512, 2) void gemm1_8p(
    const __bf16* __restrict__ xb, const __bf16* __restrict__ W1T,
    const float* __restrict__ b1,
    const int* __restrict__ token_id, const int* __restrict__ tile_e,
    const int* __restrict__ tile_rb, const int* __restrict__ ntiles,
    __bf16* __restrict__ h)
{
    extern __shared__ __bf16 lds[];   // 3 * 16384 elems
    int flat = blockIdx.x;
    int c8 = flat & 7, r = flat >> 3;
    int mti = r >> 4, nb = r & 15;
    int mt = c8 * 9 + mti;
    if (mt >= *ntiles) return;
    int e = tile_e[mt], rb = tile_rb[mt];
    int n0 = nb * 256;

    int tid = threadIdx.x, lane = tid & 63, wid = tid >> 6;
    int wr = wid >> 2, wc = wid & 3;
    int cl = lane & 15, cq = lane >> 4;

    // stage source (per-thread): row srow of each subtile, swizzled chunk
    int srow = tid >> 2;
    int schunk = (tid & 3) ^ ((tid >> 3) & 3);
    const __bf16* ag[2];
#pragma unroll
    for (int hm = 0; hm < 2; hm++) {
        int tok = token_id[rb + hm * 128 + srow];
        if (tok < 0) tok = 0;   // pad rows: finite garbage, never combined
        ag[hm] = xb + (size_t)tok * EMB + schunk * 8;
    }
    const __bf16* bg[2];
#pragma unroll
    for (int hn = 0; hn < 2; hn++)
        bg[hn] = W1T + ((size_t)e * FF + (size_t)(n0 + hn * 128 + srow)) * EMB + schunk * 8;

    // stage LDS dest (wave-uniform, elems within buf)
    int sdA0 = wid * 512, sdA1 = 4096 + wid * 512;
    int sdB0 = 8192 + wid * 512, sdB1 = 12288 + wid * 512;

    // fragment read offsets (elems within buf)
    int xoffe = (cq ^ ((cl >> 1) & 3)) * 8;
    int aoff[8], boff[4];
#pragma unroll
    for (int mi = 0; mi < 8; mi++) {
        int rr = wr * 128 + mi * 16 + cl;
        aoff[mi] = (rr >> 7) * 4096 + (rr & 127) * 32 + xoffe;
    }
#pragma unroll
    for (int ni = 0; ni < 4; ni++) {
        int nn = wc * 64 + ni * 16 + cl;
        boff[ni] = 8192 + (nn >> 7) * 4096 + (nn & 127) * 32 + xoffe;
    }

    f32x4 acc[8][4];
#pragma unroll
    for (int i = 0; i < 8; i++)
#pragma unroll
        for (int j = 0; j < 4; j++) acc[i][j] = fzero();

    const int NT = EMB / 32;
    // prologue: stage tiles 0 (buf0) and 1 (buf1), 4 subtiles each in order
#pragma unroll
    for (int t0 = 0; t0 < 2; t0++) {
        __bf16* bp = lds + t0 * 16384;
        int k0 = t0 * 32;
        gl16(ag[0] + k0, bp + sdA0);
        gl16(ag[1] + k0, bp + sdA1);
        gl16(bg[0] + k0, bp + sdB0);
        gl16(bg[1] + k0, bp + sdB1);
    }
    asm volatile("s_waitcnt vmcnt(4)" ::: "memory");
    __builtin_amdgcn_s_barrier();

    int cb = 0;
#pragma unroll 1
    for (int t = 0; t < NT; t++) {
        const __bf16* cp = lds + cb * 16384;
        int sb = cb + 2; if (sb >= 3) sb -= 3;
        __bf16* sp = lds + sb * 16384;
        int kt = t + 2;
        bool do_stage = (kt < NT);
        int ko = kt * 32;

        // ---- phase 1: acc rows 0-3, read all B ----
        bf16x8 a[4], b[4];
        read_frags(cp, aoff, a, 4);
        read_frags(cp, boff, b, 4);
        if (do_stage) {
            gl16(ag[0] + ko, sp + sdA0);
            gl16(ag[1] + ko, sp + sdA1);
        }
        GEMM_PHASE(a, b, 0)
        __builtin_amdgcn_s_barrier();

        // ---- phase 2: acc rows 4-7, reuse B ----
        bf16x8 a2[4];
        read_frags(cp, aoff + 4, a2, 4);
        if (do_stage) {
            gl16(bg[0] + ko, sp + sdB0);
            gl16(bg[1] + ko, sp + sdB1);
        }
        GEMM_PHASE(a2, b, 4)
        if (t < NT - 2)       { asm volatile("s_waitcnt vmcnt(4)" ::: "memory"); }
        else if (t == NT - 2) { asm volatile("s_waitcnt vmcnt(0)" ::: "memory"); }
        __builtin_amdgcn_s_barrier();

        cb = cb + 1; if (cb >= 3) cb = 0;
    }

    // epilogue: bias + gelu -> bf16 h
    const float* b1g = b1 + (size_t)e * FF + n0;
#pragma unroll
    for (int mi = 0; mi < 8; mi++) {
#pragma unroll
        for (int ni = 0; ni < 4; ni++) {
            int col = wc * 64 + ni * 16 + cl;
            float bias = b1g[col];
#pragma unroll
            for (int j = 0; j < 4; j++) {
                int row = wr * 128 + mi * 16 + cq * 4 + j;
                float v = acc[mi][ni][j] + bias;
                h[(size_t)(rb + row) * FF + n0 + col] = (__bf16)gelu_f(v);
            }
        }
    }
}

// y_z[slot] = h[slot][koff:koff+KC] @ W2T[e][:, koff:koff+KC]^T ; N-tile 256.
__global__ __launch_bounds__(512, 2) void gemm2_8p(
    const __bf16* __restrict__ h, const __bf16* __restrict__ W2T,
    const int* __restrict__ tile_e, const int* __restrict__ tile_rb,
    const int* __restrict__ ntiles,
    float* __restrict__ y0, float* __restrict__ y1, int nsplit)
{
    extern __shared__ __bf16 lds[];
    int flat = blockIdx.x;
    int c8 = flat & 7, r = flat >> 3;
    int z = r / 36; int r36 = r - z * 36;
    int mti = r36 >> 2, nb = r36 & 3;
    int mt = c8 * 9 + mti;
    if (mt >= *ntiles) return;
    int e = tile_e[mt], rb = tile_rb[mt];
    int n0 = nb * 256;
    int KC = FF / nsplit;
    int koff = z * KC;
    float* y = z ? y1 : y0;

    int tid = threadIdx.x, lane = tid & 63, wid = tid >> 6;
    int wr = wid >> 2, wc = wid & 3;
    int cl = lane & 15, cq = lane >> 4;

    int srow = tid >> 2;
    int schunk = (tid & 3) ^ ((tid >> 3) & 3);
    const __bf16* ag[2];
#pragma unroll
    for (int hm = 0; hm < 2; hm++)
        ag[hm] = h + (size_t)(rb + hm * 128 + srow) * FF + koff + schunk * 8;
    const __bf16* bg[2];
#pragma unroll
    for (int hn = 0; hn < 2; hn++)
        bg[hn] = W2T + ((size_t)e * EMB + (size_t)(n0 + hn * 128 + srow)) * FF + koff + schunk * 8;

    int sdA0 = wid * 512, sdA1 = 4096 + wid * 512;
    int sdB0 = 8192 + wid * 512, sdB1 = 12288 + wid * 512;

    int xoffe = (cq ^ ((cl >> 1) & 3)) * 8;
    int aoff[8], boff[4];
#pragma unroll
    for (int mi = 0; mi < 8; mi++) {
        int rr = wr * 128 + mi * 16 + cl;
        aoff[mi] = (rr >> 7) * 4096 + (rr & 127) * 32 + xoffe;
    }
#pragma unroll
    for (int ni = 0; ni < 4; ni++) {
        int nn = wc * 64 + ni * 16 + cl;
        boff[ni] = 8192 + (nn >> 7) * 4096 + (nn & 127) * 32 + xoffe;
    }

    f32x4 acc[8][4];
#pragma unroll
    for (int i = 0; i < 8; i++)
#pragma unroll
        for (int j = 0; j < 4; j++) acc[i][j] = fzero();

    const int NT = KC / 32;
#pragma unroll
    for (int t0 = 0; t0 < 2; t0++) {
        __bf16* bp = lds + t0 * 16384;
        int k0 = t0 * 32;
        gl16(ag[0] + k0, bp + sdA0);
        gl16(ag[1] + k0, bp + sdA1);
        gl16(bg[0] + k0, bp + sdB0);
        gl16(bg[1] + k0, bp + sdB1);
    }
    asm volatile("s_waitcnt vmcnt(4)" ::: "memory");
    __builtin_amdgcn_s_barrier();

    int cb = 0;
#pragma unroll 1
    for (int t = 0; t < NT; t++) {
        const __bf16* cp = lds + cb * 16384;
        int sb = cb + 2; if (sb >= 3) sb -= 3;
        __bf16* sp = lds + sb * 16384;
        int kt = t + 2;
        bool do_stage = (kt < NT);
        int ko = kt * 32;

        bf16x8 a[4], b[4];
        read_frags(cp, aoff, a, 4);
        read_frags(cp, boff, b, 4);
        if (do_stage) {
            gl16(ag[0] + ko, sp + sdA0);
            gl16(ag[1] + ko, sp + sdA1);
        }
        GEMM_PHASE(a, b, 0)
        __builtin_amdgcn_s_barrier();

        bf16x8 a2[4];
        read_frags(cp, aoff + 4, a2, 4);
        if (do_stage) {
            gl16(bg[0] + ko, sp + sdB0);
            gl16(bg[1] + ko, sp + sdB1);
        }
        GEMM_PHASE(a2, b, 4)
        if (t < NT - 2)       { asm volatile("s_waitcnt vmcnt(4)" ::: "memory"); }
        else if (t == NT - 2) { asm volatile("s_waitcnt vmcnt(0)" ::: "memory"); }
        __builtin_amdgcn_s_barrier();

        cb = cb + 1; if (cb >= 3) cb = 0;
    }

#pragma unroll
    for (int mi = 0; mi < 8; mi++) {
#pragma unroll
        for (int ni = 0; ni < 4; ni++) {
            int col = wc * 64 + ni * 16 + cl;
#pragma unroll
            for (int j = 0; j < 4; j++) {
                int row = wr * 128 + mi * 16 + cq * 4 + j;
                y[(size_t)(rb + row) * EMB + n0 + col] = acc[mi][ni][j];
            }
        }
    }
}

extern "C" void kernel_launch(void* const* d_in, const int* in_sizes, int n_in,
                              void* d_out, int out_size, void* d_ws, size_t ws_size,
                              hipStream_t stream)
{
    const float* x   = (const float*)d_in[0];
    const float* gW  = (const float*)d_in[1];
    const float* gb  = (const float*)d_in[2];
    const float* W1  = (const float*)d_in[3];
    const float* b1  = (const float*)d_in[4];
    const float* W2  = (const float*)d_in[5];
    const float* b2  = (const float*)d_in[6];
    float* out = (float*)d_out;

    char* ws = (char*)d_ws;
    int*   counts  = (int*)(ws + WS_COUNTS);
    int*   cursors = (int*)(ws + WS_CURSORS);
    float* ssum    = (float*)(ws + WS_SSUM);
    int*   ntiles  = (int*)(ws + WS_NTILES);
    int*   base    = (int*)(ws + WS_BASE);
    int*   tile_e  = (int*)(ws + WS_TILE_E);
    int*   tile_rb = (int*)(ws + WS_TILE_RB);
    int*   tk_idx  = (int*)(ws + WS_TKIDX);
    float* tk_w    = (float*)(ws + WS_TKW);
    int*   slot_of = (int*)(ws + WS_SLOT);
    int*   token_id= (int*)(ws + WS_TOKID);
    float* roww    = (float*)(ws + WS_ROWW);

    __bf16* W1T  = (__bf16*)(ws + WS_BIG2);
    __bf16* xb   = (__bf16*)(ws + WS_BIG2 + SZ_W1T);
    __bf16* W2T  = (__bf16*)(ws + WS_BIG2 + SZ_W1T + SZ_XB);
    __bf16* hbuf = (__bf16*)(ws + WS_BIG2 + SZ_W1T + SZ_XB + SZ_W2T);
    size_t fixedend = WS_BIG2 + SZ_W1T + SZ_XB + SZ_W2T;

    float* y0 = (float*)(ws + WS_BIG2);              // aliases W1T+xb (dead after gemm1)
    float* y1 = (float*)(ws + fixedend + SZ_H);      // only used when split
    int nsplit = (ws_size >= fixedend + SZ_H + SZ_Y) ? 2 : 1;

    hipFuncSetAttribute((const void*)gemm1_8p, hipFuncAttributeMaxDynamicSharedMemorySize, 98304);
    hipFuncSetAttribute((const void*)gemm2_8p, hipFuncAttributeMaxDynamicSharedMemorySize, 98304);

    hipMemsetAsync(ws + WS_COUNTS, 0, 2080, stream);
    hipMemsetAsync(ws + WS_TOKID, 0xFF, (size_t)MAXROWS * 4, stream);

    cvt_x_kernel<<<TTOK * EMB / 2048, 256, 0, stream>>>(x, xb);
    transpose_cvt_kernel<<<dim3(EMB / 64, FF / 64, NE), 256, 0, stream>>>(W1, W1T, EMB, FF);
    transpose_cvt_kernel<<<dim3(FF / 64, EMB / 64, NE), 256, 0, stream>>>(W2, W2T, FF, EMB);

    gate_kernel<<<TTOK / 4, 256, 0, stream>>>(x, gW, gb, counts, ssum, tk_idx, tk_w);
    route_build_kernel<<<1, 64, 0, stream>>>(counts, ssum, ntiles, base, tile_e, tile_rb,
                                             out + (size_t)TTOK * EMB);
    scatter_kernel<<<TTOK / 256, 256, 0, stream>>>(tk_idx, tk_w, base, cursors, token_id, roww, slot_of);

    gemm1_8p<<<8 * 9 * 16, 512, 98304, stream>>>(
        xb, W1T, b1, token_id, tile_e, tile_rb, ntiles, hbuf);
    gemm2_8p<<<8 * 9 * 4 * nsplit, 512, 98304, stream>>>(
        hbuf, W2T, tile_e, tile_rb, ntiles, y0, y1, nsplit);
    combine_kernel<<<TTOK, 256, 0, stream>>>(y0, y1, nsplit, slot_of, tk_idx, tk_w, b2, out);
}